// Round 6
// baseline (359.916 us; speedup 1.0000x reference)
//
#include <hip/hip_runtime.h>
#include <hip/hip_bf16.h>

typedef __attribute__((ext_vector_type(4))) float f32x4;
typedef __attribute__((ext_vector_type(8))) short bf16x8;
typedef __attribute__((ext_vector_type(4))) short s16x4;

#define C_DIM 512
#define N_PIX 2304
#define N_BATCH 8
#define ATT_SCALE 0.04419417382415922f
#define NJB 9                       // N_PIX / 256 (s-kernel j-tiles)

typedef __attribute__((address_space(3))) unsigned int lds_u32;
typedef const __attribute__((address_space(1))) unsigned int glob_u32;

__device__ __forceinline__ void gl2lds16(const __hip_bfloat16* g, __hip_bfloat16* l)
{
    __builtin_amdgcn_global_load_lds((glob_u32*)g, (lds_u32*)l, 16, 0, 0);
}

#define GBAR() __builtin_amdgcn_s_barrier()
#define GVM0() asm volatile("s_waitcnt vmcnt(0)" ::: "memory")

// ===========================================================================
// ALGEBRAIC FOLDS (round-6):
//  S = (XlWq^T+bq)(XgWk^T+bk)^T scores: row-constant terms cancel in softmax.
//    scores·1/sc = Xl·(Wq^T Wk)·Xg^T + v[m]   (+ u[n] + c0, dropped: cancel)
//    matT[c2][c1] = sum_o Wk[o,c2]Wq[o,c1]  (gemm_bt(WkT, WqT))
//    T = gemm_bt(Xlt, matT)  -> replaces Q-proj AND K-proj
//    v[m] = Xgt[m,:]·wv, wv[c] = sum_o Wk[o,c]bq[o]
//  Vp[o,m] = Wo·(XgWv^T+bv)^T = Xg·Wov^T + bov  -> replaces V-proj + V' GEMM
//    Wov = gemm_bt(Wo, WvT), bov = Wo·bv
// ===========================================================================

// ---------------------------------------------------------------------------
// s_only: 256x256 8-phase (round-1-proven structure), S-tiles only (648 blks).
// Pu[n,m] = exp(SC*(sum_c T[n,c]Xgt[m,c] + v[m])), rp row-sum partials.
// ---------------------------------------------------------------------------

#define BAR()  __builtin_amdgcn_s_barrier()
#define LGK0() asm volatile("s_waitcnt lgkmcnt(0)" ::: "memory")
#define VM4()  asm volatile("s_waitcnt vmcnt(4)" ::: "memory")
#define VM0()  asm volatile("s_waitcnt vmcnt(0)" ::: "memory")
#define PRIO(p) __builtin_amdgcn_s_setprio(p)

#define STAGE_A(dd, hh, tk) do { \
    _Pragma("unroll") \
    for (int ss = 0; ss < 2; ++ss) { \
        const int ur0 = wave * 16 + ss * 8; \
        const int row0 = ((ur0 >> 6) << 7) + (hh) * 64 + (ur0 & 63); \
        gl2lds16(gA + (size_t)row0 * C_DIM + (tk) * 64, \
                 (__hip_bfloat16*)&LA[dd][row0 * 64]); \
    } } while (0)

#define STAGE_B(dd, bb, tk) do { \
    _Pragma("unroll") \
    for (int ss = 0; ss < 2; ++ss) { \
        const int ur0 = wave * 16 + ss * 8; \
        const int row0 = ((ur0 >> 5) << 6) + (bb) * 32 + (ur0 & 31); \
        gl2lds16(gB + (size_t)row0 * C_DIM + (tk) * 64, \
                 (__hip_bfloat16*)&LB[dd][row0 * 64]); \
    } } while (0)

#define LOAD_A(dd, hh) do { \
    _Pragma("unroll") \
    for (int tt = 0; tt < 4; ++tt) { \
        const int rb = (wr * 128 + (hh) * 64 + tt * 16 + fr) * 64; \
        _Pragma("unroll") \
        for (int kk = 0; kk < 2; ++kk) \
            aF[tt][kk] = *(const bf16x8*)(&LA[dd][rb + (((kk * 4 + fq) ^ sw) << 3)]); \
    } } while (0)

#define LOAD_B(dd, bb, dst) do { \
    _Pragma("unroll") \
    for (int s2 = 0; s2 < 2; ++s2) { \
        const int rb = (wc * 64 + (bb) * 32 + s2 * 16 + fr) * 64; \
        _Pragma("unroll") \
        for (int kk = 0; kk < 2; ++kk) \
            dst[s2][kk] = *(const bf16x8*)(&LB[dd][rb + (((kk * 4 + fq) ^ sw) << 3)]); \
    } } while (0)

#define MFMA_Q(HH, BB, bsrc) do { \
    _Pragma("unroll") \
    for (int tt = 0; tt < 4; ++tt) \
    _Pragma("unroll") \
    for (int s2 = 0; s2 < 2; ++s2) \
    _Pragma("unroll") \
    for (int kk = 0; kk < 2; ++kk) \
        acc[(HH) * 4 + tt][(BB) * 2 + s2] = __builtin_amdgcn_mfma_f32_16x16x32_bf16( \
            aF[tt][kk], bsrc[s2][kk], acc[(HH) * 4 + tt][(BB) * 2 + s2], 0, 0, 0); \
    } while (0)

template<int NS>
__global__ __launch_bounds__(512, 2)
void s_only(const __hip_bfloat16* __restrict__ Tm, const __hip_bfloat16* __restrict__ Xgt,
            __hip_bfloat16* __restrict__ Pu, float* __restrict__ rp,
            const float* __restrict__ vvec, int bz_off, long sPu)
{
    __shared__ __hip_bfloat16 LA[2][256 * 64];
    __shared__ __hip_bfloat16 LB[2][256 * 64];

    const int lin = blockIdx.x;
    const int bz  = lin % NS + bz_off;
    const int t   = lin / NS;
    const int ib  = t / 9;
    const int jb  = t % 9;
    const long sQ = (long)N_PIX * C_DIM;

    const __hip_bfloat16* A = Tm  + (size_t)bz * sQ;
    const __hip_bfloat16* B = Xgt + (size_t)bz * sQ;
    __hip_bfloat16* D = Pu + (size_t)bz * (size_t)sPu;

    const int i0 = ib * 256;
    const int j0 = jb * 256;

    const int tid  = threadIdx.x;
    const int lane = tid & 63;
    const int wave = tid >> 6;

    const int lrow = lane >> 3;
    const int lcs  = (lane & 7) ^ lrow;           // XOR chunk swizzle (store side)
    const __hip_bfloat16* gA = A + (size_t)(i0 + lrow) * C_DIM + lcs * 8;
    const __hip_bfloat16* gB = B + (size_t)(j0 + lrow) * C_DIM + lcs * 8;

    const int fr = lane & 15;
    const int fq = lane >> 4;
    const int sw = fr & 7;                        // row&7 on read side
    const int wr = wave >> 2;                     // 0..1 (row wave)
    const int wc = wave & 3;                      // 0..3 (col wave)

    f32x4 acc[8][4];
#pragma unroll
    for (int a = 0; a < 8; ++a)
#pragma unroll
        for (int b = 0; b < 4; ++b)
            acc[a][b] = (f32x4){0.f, 0.f, 0.f, 0.f};

    bf16x8 aF[4][2], bF0[2][2], bF1[2][2];

    // prologue: tile0 (4 halves) + tile1 {A0,B1}; vmcnt(4) -> tile0 landed
    STAGE_A(0, 0, 0); STAGE_B(0, 0, 0); STAGE_B(0, 1, 0); STAGE_A(0, 1, 0);
    STAGE_A(1, 0, 1); STAGE_B(1, 1, 1);
    VM4();
    BAR();

    for (int kt = 0; kt < 6; ++kt) {
        const int d = kt & 1, e = d ^ 1;
        LOAD_A(d, 0); LOAD_B(d, 0, bF0);
        STAGE_A(e, 1, kt + 1);
        BAR(); LGK0();
        PRIO(1); MFMA_Q(0, 0, bF0); PRIO(0);
        BAR();
        LOAD_B(d, 1, bF1);
        STAGE_B(e, 0, kt + 1);
        BAR(); LGK0();
        PRIO(1); MFMA_Q(0, 1, bF1); PRIO(0);
        BAR();
        LOAD_A(d, 1);
        STAGE_A(d, 0, kt + 2);
        BAR(); LGK0();
        PRIO(1); MFMA_Q(1, 1, bF1); PRIO(0);
        BAR();
        STAGE_B(d, 1, kt + 2);
        VM4();
        BAR();
        PRIO(1); MFMA_Q(1, 0, bF0); PRIO(0);
        BAR();
    }
    {   // K-tile 6 (buf 0): stage only tile-7 {A1,B0}
        LOAD_A(0, 0); LOAD_B(0, 0, bF0);
        STAGE_A(1, 1, 7);
        BAR(); LGK0();
        PRIO(1); MFMA_Q(0, 0, bF0); PRIO(0);
        BAR();
        LOAD_B(0, 1, bF1);
        STAGE_B(1, 0, 7);
        BAR(); LGK0();
        PRIO(1); MFMA_Q(0, 1, bF1); PRIO(0);
        BAR();
        LOAD_A(0, 1);
        BAR(); LGK0();
        PRIO(1); MFMA_Q(1, 1, bF1); PRIO(0);
        BAR();
        VM0();
        BAR();
        PRIO(1); MFMA_Q(1, 0, bF0); PRIO(0);
        BAR();
    }
    {   // K-tile 7 (buf 1): no staging
        LOAD_A(1, 0); LOAD_B(1, 0, bF0);
        BAR(); LGK0();
        PRIO(1); MFMA_Q(0, 0, bF0); PRIO(0);
        BAR();
        LOAD_B(1, 1, bF1);
        BAR(); LGK0();
        PRIO(1); MFMA_Q(0, 1, bF1); PRIO(0);
        BAR();
        LOAD_A(1, 1);
        BAR(); LGK0();
        PRIO(1); MFMA_Q(1, 1, bF1); PRIO(0);
        BAR();
        PRIO(1); MFMA_Q(1, 0, bF0); PRIO(0);
    }

    // epilogue: exp(SC*(acc + v[m])), rp partials
    float vb[4];
#pragma unroll
    for (int b = 0; b < 4; ++b)
        vb[b] = vvec[(size_t)bz * N_PIX + j0 + wc * 64 + b * 16 + fr];

    float rpart[8][4];
#pragma unroll
    for (int a = 0; a < 8; ++a)
#pragma unroll
        for (int r = 0; r < 4; ++r)
            rpart[a][r] = 0.f;
#pragma unroll
    for (int a = 0; a < 8; ++a) {
        const int grow = i0 + wr * 128 + a * 16 + fq * 4;
#pragma unroll
        for (int b = 0; b < 4; ++b) {
            const int col = j0 + wc * 64 + b * 16 + fr;
#pragma unroll
            for (int r = 0; r < 4; ++r) {
                float v = __expf(ATT_SCALE * (acc[a][b][r] + vb[b]));
                rpart[a][r] += v;
                D[(size_t)(grow + r) * N_PIX + col] = __float2bfloat16(v);
            }
        }
    }
#pragma unroll
    for (int m = 1; m < 16; m <<= 1)
#pragma unroll
        for (int a = 0; a < 8; ++a)
#pragma unroll
            for (int r = 0; r < 4; ++r)
                rpart[a][r] += __shfl_xor(rpart[a][r], m);
    float* rsl = (float*)&LA[0][0];
    __syncthreads();
    if (fr == 0) {
#pragma unroll
        for (int a = 0; a < 8; ++a)
#pragma unroll
            for (int r = 0; r < 4; ++r)
                rsl[wave * 128 + a * 16 + fq * 4 + r] = rpart[a][r];
    }
    __syncthreads();
    if (tid < 256) {
        const int wr2 = tid >> 7, rl = tid & 127;
        float s = rsl[(wr2 * 4 + 0) * 128 + rl] + rsl[(wr2 * 4 + 1) * 128 + rl]
                + rsl[(wr2 * 4 + 2) * 128 + rl] + rsl[(wr2 * 4 + 3) * 128 + rl];
        rp[((size_t)jb * N_BATCH + bz) * N_PIX + i0 + tid] = s;
    }
}

#undef STAGE_A
#undef STAGE_B
#undef LOAD_A
#undef LOAD_B
#undef MFMA_Q
#undef BAR
#undef LGK0
#undef VM4
#undef VM0
#undef PRIO

// ---------------------------------------------------------------------------
// PV + output (round-5 proven, unchanged): out[o,n]=rinv[n]*sum_m Vp[o,m]Pu[n,m]+bo
// ---------------------------------------------------------------------------

#define PV_STAGE(ee, tk) do { \
    _Pragma("unroll") \
    for (int ss = 0; ss < 2; ++ss) \
        gl2lds16(ga + (size_t)ss * 8 * N_PIX + (tk) * 64, \
                 laA + (ee) * (64 * 64) + ss * 8 * 64); \
    _Pragma("unroll") \
    for (int ss = 0; ss < 4; ++ss) \
        gl2lds16(gb + (size_t)ss * 8 * N_PIX + (tk) * 64, \
                 laB + (ee) * (128 * 64) + ss * 8 * 64); \
    } while (0)

#define PV_COMP(dd) do { \
    _Pragma("unroll") \
    for (int kk = 0; kk < 2; ++kk) { \
        bf16x8 af[2], bfr[4]; \
        const int ca = ((kk * 4 + fq) ^ sw) << 3; \
        _Pragma("unroll") \
        for (int tt = 0; tt < 2; ++tt) \
            af[tt]  = *(const bf16x8*)(&As[dd][(wi + tt * 16 + fr) * 64 + ca]); \
        _Pragma("unroll") \
        for (int tt = 0; tt < 4; ++tt) \
            bfr[tt] = *(const bf16x8*)(&Bs[dd][(wj + tt * 16 + fr) * 64 + ca]); \
        _Pragma("unroll") \
        for (int a = 0; a < 2; ++a) \
        _Pragma("unroll") \
        for (int b = 0; b < 4; ++b) \
            acc[a][b] = __builtin_amdgcn_mfma_f32_16x16x32_bf16( \
                af[a], bfr[b], acc[a][b], 0, 0, 0); \
    } } while (0)

template<int NS>
__global__ __launch_bounds__(256)
void pv_out(const __hip_bfloat16* __restrict__ Vp, const __hip_bfloat16* __restrict__ Pu,
            float* __restrict__ out, const float* __restrict__ bo,
            const float* __restrict__ rp, int bz_off, long sPu)
{
    __shared__ __hip_bfloat16 As[2][64 * 64];
    __shared__ __hip_bfloat16 Bs[2][128 * 64];

    const int lin = blockIdx.x;
    const int bz  = lin % NS + bz_off;
    const int t   = lin / NS;
    const int ib  = t % 8;
    const int jb  = t / 8;
    const int i0  = ib * 64;
    const int j0  = jb * 128;

    const long sCN = (long)C_DIM * N_PIX;
    const __hip_bfloat16* A = Vp + (size_t)bz * sCN;
    const __hip_bfloat16* B = Pu + (size_t)bz * (size_t)sPu;
    float* D = out + (size_t)bz * sCN;

    const int tid  = threadIdx.x;
    const int lane = tid & 63;
    const int wave = tid >> 6;

    const int lrow = lane >> 3;
    const int lcs  = (lane & 7) ^ lrow;
    const __hip_bfloat16* ga = A + (size_t)(i0 + wave * 16 + lrow) * N_PIX + lcs * 8;
    const __hip_bfloat16* gb = B + (size_t)(j0 + wave * 32 + lrow) * N_PIX + lcs * 8;
    __hip_bfloat16* laA = &As[0][wave * 16 * 64];
    __hip_bfloat16* laB = &Bs[0][wave * 32 * 64];

    const int fr = lane & 15;
    const int fq = lane >> 4;
    const int sw = fr & 7;
    const int wi = (wave >> 1) * 32;
    const int wj = (wave & 1) * 64;

    f32x4 acc[2][4];
#pragma unroll
    for (int a = 0; a < 2; ++a)
#pragma unroll
        for (int b = 0; b < 4; ++b)
            acc[a][b] = (f32x4){0.f, 0.f, 0.f, 0.f};

    PV_STAGE(0, 0);
    GVM0(); GBAR();

#pragma unroll 1
    for (int kt = 0; kt < 34; kt += 2) {
        PV_STAGE(1, kt + 1);
        PV_COMP(0);
        GVM0(); GBAR();
        PV_STAGE(0, kt + 2);
        PV_COMP(1);
        GVM0(); GBAR();
    }
    PV_STAGE(1, 35);
    PV_COMP(0);
    GVM0(); GBAR();
    PV_COMP(1);

    const int orow = fq * 4;
    float rjv[4];
#pragma unroll
    for (int b = 0; b < 4; ++b) {
        int j = j0 + wj + b * 16 + fr;
        float s = 0.f;
#pragma unroll
        for (int jj = 0; jj < NJB; ++jj)
            s += rp[((size_t)jj * N_BATCH + bz) * N_PIX + j];
        rjv[b] = 1.f / s;
    }

#pragma unroll
    for (int a = 0; a < 2; ++a) {
        int ibx = i0 + wi + a * 16 + orow;
#pragma unroll
        for (int r = 0; r < 4; ++r) {
            float bi = bo[ibx + r];
#pragma unroll
            for (int b = 0; b < 4; ++b) {
                int j = j0 + wj + b * 16 + fr;
                D[(size_t)(ibx + r) * N_PIX + j] = acc[a][b][r] * rjv[b] + bi;
            }
        }
    }
}

#undef PV_STAGE
#undef PV_COMP

// ---------------------------------------------------------------------------
// 128x128 K=512 dbuf GEMM machinery (round-5 proven), shared by proj2 / wmix.
// ---------------------------------------------------------------------------

#define PJ_STAGE(ee, tk) do { \
    _Pragma("unroll") \
    for (int ss = 0; ss < 4; ++ss) { \
        gl2lds16(ga + (size_t)ss * 8 * C_DIM + (tk) * 64, \
                 laA + (ee) * (128 * 64) + ss * 8 * 64); \
        gl2lds16(gb + (size_t)ss * 8 * C_DIM + (tk) * 64, \
                 laB + (ee) * (128 * 64) + ss * 8 * 64); \
    } } while (0)

#define PJ_COMP(dd) do { \
    _Pragma("unroll") \
    for (int kk = 0; kk < 2; ++kk) { \
        bf16x8 af[4], bfr[4]; \
        const int ca = ((kk * 4 + fq) ^ sw) << 3; \
        _Pragma("unroll") \
        for (int tt = 0; tt < 4; ++tt) { \
            af[tt]  = *(const bf16x8*)(&As[dd][(wi + tt * 16 + fr) * 64 + ca]); \
            bfr[tt] = *(const bf16x8*)(&Bs[dd][(wj + tt * 16 + fr) * 64 + ca]); \
        } \
        _Pragma("unroll") \
        for (int a = 0; a < 4; ++a) \
        _Pragma("unroll") \
        for (int b = 0; b < 4; ++b) \
            acc[a][b] = __builtin_amdgcn_mfma_f32_16x16x32_bf16( \
                af[a], bfr[b], acc[a][b], 0, 0, 0); \
    } } while (0)

#define PJ_LOOP() do { \
    PJ_STAGE(0, 0); \
    GVM0(); GBAR(); \
    _Pragma("unroll 1") \
    for (int kt = 0; kt < 6; kt += 2) { \
        PJ_STAGE(1, kt + 1); \
        PJ_COMP(0); \
        GVM0(); GBAR(); \
        PJ_STAGE(0, kt + 2); \
        PJ_COMP(1); \
        GVM0(); GBAR(); \
    } \
    PJ_STAGE(1, 7); \
    PJ_COMP(0); \
    GVM0(); GBAR(); \
    PJ_COMP(1); \
    } while (0)

// ---------------------------------------------------------------------------
// proj2: mat0: T = gemm_bt(Xlt, matT)   (no bias, standard [n,c] store)
//        mat1: Vp = gemm_bt(Xgt, Wov)+bov, stored TRANSPOSED [o,m] via LDS.
// Grid 16 x 72 = 1152.
// ---------------------------------------------------------------------------
__global__ __launch_bounds__(256)
void proj2(const __hip_bfloat16* __restrict__ Xlt,
           const __hip_bfloat16* __restrict__ Xgt,
           const __hip_bfloat16* __restrict__ matT,
           const __hip_bfloat16* __restrict__ Wov,
           const float* __restrict__ bovp,
           __hip_bfloat16* __restrict__ Tm,
           __hip_bfloat16* __restrict__ Vp)
{
    __shared__ __hip_bfloat16 As[2][128 * 64];
    __shared__ __hip_bfloat16 Bs[2][128 * 64];

    const int lin = blockIdx.x;
    const int s   = lin % 16;
    const int bz  = s & 7;
    const int m2  = s >> 3;
    const int t2  = lin / 16;
    const int j0  = (t2 & 3) * 128;
    const int i0  = (t2 >> 2) * 128;
    const long sNC = (long)N_PIX * C_DIM;

    const __hip_bfloat16* Ab = (m2 ? Xgt : Xlt) + (size_t)bz * sNC;
    const __hip_bfloat16* Bb = m2 ? Wov : matT;

    const int tid  = threadIdx.x;
    const int lane = tid & 63;
    const int wave = tid >> 6;

    const int lrow = lane >> 3;
    const int lcs  = (lane & 7) ^ lrow;
    const __hip_bfloat16* ga = Ab + (size_t)(i0 + wave * 32 + lrow) * C_DIM + lcs * 8;
    const __hip_bfloat16* gb = Bb + (size_t)(j0 + wave * 32 + lrow) * C_DIM + lcs * 8;
    __hip_bfloat16* laA = &As[0][wave * 32 * 64];
    __hip_bfloat16* laB = &Bs[0][wave * 32 * 64];

    const int fr = lane & 15;
    const int fq = lane >> 4;
    const int sw = fr & 7;
    const int wi = (wave >> 1) * 64;
    const int wj = (wave & 1) * 64;

    f32x4 acc[4][4];
#pragma unroll
    for (int a = 0; a < 4; ++a)
#pragma unroll
        for (int b = 0; b < 4; ++b)
            acc[a][b] = (f32x4){0.f, 0.f, 0.f, 0.f};

    PJ_LOOP();

    const int orow = fq * 4;
    if (m2 == 0) {
        __hip_bfloat16* D = Tm + (size_t)bz * sNC;
#pragma unroll
        for (int a = 0; a < 4; ++a) {
            int ibx = i0 + wi + a * 16 + orow;
#pragma unroll
            for (int b = 0; b < 4; ++b) {
                int j = j0 + wj + b * 16 + fr;
#pragma unroll
                for (int r = 0; r < 4; ++r)
                    D[(size_t)(ibx + r) * C_DIM + j] = __float2bfloat16(acc[a][b][r]);
            }
        }
    } else {
        // transposed store: Vp[(j0+jj)*N_PIX + (i0+ii)] via padded-LDS transpose
        __hip_bfloat16* Dvp = Vp + (size_t)bz * sNC;
        float bvb[4];
#pragma unroll
        for (int b = 0; b < 4; ++b)
            bvb[b] = bovp[j0 + wj + b * 16 + fr];
        __syncthreads();
        __hip_bfloat16* Tt = (__hip_bfloat16*)&As[0][0];   // [128][65] bf16
#pragma unroll
        for (int h = 0; h < 2; ++h) {
            if ((wave & 1) == h) {
#pragma unroll
                for (int a = 0; a < 4; ++a) {
                    int rl = wi + a * 16 + orow;
#pragma unroll
                    for (int b = 0; b < 4; ++b) {
                        int cl = b * 16 + fr;
#pragma unroll
                        for (int r = 0; r < 4; ++r)
                            Tt[(rl + r) * 65 + cl] =
                                __float2bfloat16(acc[a][b][r] + bvb[b]);
                    }
                }
            }
            __syncthreads();
            {
                const int lj = tid >> 2, ic = (tid & 3) * 32;
                union { __hip_bfloat16 h8[32]; int4 v4[4]; } u;
#pragma unroll
                for (int q = 0; q < 32; ++q)
                    u.h8[q] = Tt[(ic + q) * 65 + lj];
                __hip_bfloat16* dst = Dvp + (size_t)(j0 + h * 64 + lj) * N_PIX + i0 + ic;
#pragma unroll
                for (int q4 = 0; q4 < 4; ++q4)
                    ((int4*)dst)[q4] = u.v4[q4];
            }
            __syncthreads();
        }
    }
}

// ---------------------------------------------------------------------------
// wmix: blocks [0,16): matT = gemm_bt(WkT, WqT); [16,32): Wov = gemm_bt(Wo_bf, WvT);
//       blocks [32,104): v[b,m] = Xgt[b,m,:]·wv  (72 blocks x 256 rows)
// ---------------------------------------------------------------------------
__global__ __launch_bounds__(256)
void wmix(const __hip_bfloat16* __restrict__ WkT, const __hip_bfloat16* __restrict__ WqT,
          const __hip_bfloat16* __restrict__ wo_bf, const __hip_bfloat16* __restrict__ WvT,
          __hip_bfloat16* __restrict__ matT, __hip_bfloat16* __restrict__ Wov,
          const __hip_bfloat16* __restrict__ Xgt, const float* __restrict__ wvbuf,
          float* __restrict__ vvec)
{
    __shared__ __hip_bfloat16 As[2][128 * 64];
    __shared__ __hip_bfloat16 Bs[2][128 * 64];

    const int lin = blockIdx.x;
    const int tid = threadIdx.x;

    if (lin >= 32) {
        // v-blocks
        float* wvs = (float*)&As[0][0];
        wvs[tid] = wvbuf[tid];
        wvs[tid + 256] = wvbuf[tid + 256];
        __syncthreads();
        const int blk = lin - 32;
        const int b   = blk / 9;
        const int m0  = (blk % 9) * 256;
        const __hip_bfloat16* row = Xgt + ((size_t)b * N_PIX + m0 + tid) * C_DIM;
        float acc = 0.f;
#pragma unroll 4
        for (int c8 = 0; c8 < 64; ++c8) {
            union { bf16x8 v; __hip_bfloat16 h[8]; } u;
            u.v = *(const bf16x8*)(row + c8 * 8);
#pragma unroll
            for (int j = 0; j < 8; ++j)
                acc += __bfloat162float(u.h[j]) * wvs[c8 * 8 + j];
        }
        vvec[(size_t)b * N_PIX + m0 + tid] = acc;
        return;
    }

    const int m2 = lin >> 4;
    const int t2 = lin & 15;
    const int j0 = (t2 & 3) * 128;
    const int i0 = (t2 >> 2) * 128;

    const __hip_bfloat16* Ab = m2 ? wo_bf : WkT;
    const __hip_bfloat16* Bb = m2 ? WvT   : WqT;
    __hip_bfloat16* D = m2 ? Wov : matT;

    const int lane = tid & 63;
    const int wave = tid >> 6;
    const int lrow = lane >> 3;
    const int lcs  = (lane & 7) ^ lrow;
    const __hip_bfloat16* ga = Ab + (size_t)(i0 + wave * 32 + lrow) * C_DIM + lcs * 8;
    const __hip_bfloat16* gb = Bb + (size_t)(j0 + wave * 32 + lrow) * C_DIM + lcs * 8;
    __hip_bfloat16* laA = &As[0][wave * 32 * 64];
    __hip_bfloat16* laB = &Bs[0][wave * 32 * 64];

    const int fr = lane & 15;
    const int fq = lane >> 4;
    const int sw = fr & 7;
    const int wi = (wave >> 1) * 64;
    const int wj = (wave & 1) * 64;

    f32x4 acc[4][4];
#pragma unroll
    for (int a = 0; a < 4; ++a)
#pragma unroll
        for (int b = 0; b < 4; ++b)
            acc[a][b] = (f32x4){0.f, 0.f, 0.f, 0.f};

    PJ_LOOP();

    const int orow = fq * 4;
#pragma unroll
    for (int a = 0; a < 4; ++a) {
        int ibx = i0 + wi + a * 16 + orow;
#pragma unroll
        for (int b = 0; b < 4; ++b) {
            int j = j0 + wj + b * 16 + fr;
#pragma unroll
            for (int r = 0; r < 4; ++r)
                D[(size_t)(ibx + r) * C_DIM + j] = __float2bfloat16(acc[a][b][r]);
        }
    }
}

#undef PJ_STAGE
#undef PJ_COMP
#undef PJ_LOOP

// ---------------------------------------------------------------------------
// prep: [0,4608)   input transpose+cast (z<8 locx->Xlt else glox->Xgt)
//       [4608,4864) Wo cast -> wo_bf
//       [4864,5056) weight transposes Wq,Wk,Wv -> WqT,WkT,WvT (bf16)
//       [5056,5058) vec1: wv[c]=sum_o Wk[o,c]bq[o]; bov[o]=Wo[o,:]·bv
// ---------------------------------------------------------------------------
__global__ __launch_bounds__(256)
void prep(const float* __restrict__ locx, const float* __restrict__ glox,
          __hip_bfloat16* __restrict__ Xlt, __hip_bfloat16* __restrict__ Xgt,
          const float* __restrict__ Wq, const float* __restrict__ Wk,
          const float* __restrict__ Wv, const float* __restrict__ Wo,
          __hip_bfloat16* __restrict__ wo_bf,
          __hip_bfloat16* __restrict__ WqT, __hip_bfloat16* __restrict__ WkT,
          __hip_bfloat16* __restrict__ WvT,
          const float* __restrict__ bq, const float* __restrict__ bv,
          float* __restrict__ wvbuf, float* __restrict__ bovbuf)
{
    __shared__ float t[64 * 65];
    const int lin = blockIdx.x;
    const int tid = threadIdx.x;

    if (lin < 4608) {
        const int z  = lin & 15;
        const int t2 = lin >> 4;
        const int c0 = (t2 & 7) * 64;
        const int n0 = (t2 >> 3) * 64;
        const size_t b = z & 7;
        const float* Xb = ((z < 8) ? locx : glox) + b * (size_t)C_DIM * N_PIX;
        __hip_bfloat16* Xt = (z < 8) ? Xlt : Xgt;

        const int n_l = tid & 63;
        const int c_b = tid >> 6;
#pragma unroll
        for (int s = 0; s < 16; ++s) {
            int c_l = c_b + s * 4;
            t[c_l * 65 + n_l] = Xb[(size_t)(c0 + c_l) * N_PIX + n0 + n_l];
        }
        __syncthreads();

        const int cc = (tid & 7) * 8;
        const int nb = tid >> 3;
#pragma unroll
        for (int it = 0; it < 2; ++it) {
            int n2 = nb + it * 32;
            union { __hip_bfloat16 h[8]; int4 v; } u;
#pragma unroll
            for (int w = 0; w < 8; ++w)
                u.h[w] = __float2bfloat16(t[(cc + w) * 65 + n2]);
            *(int4*)(&Xt[(b * N_PIX + n0 + n2) * C_DIM + c0 + cc]) = u.v;
        }
    } else if (lin < 4864) {
        const int idx = lin - 4608;          // 0..255
        const int i = (idx * 256 + tid) * 4;
        float4 f = *(const float4*)(Wo + i);
        union { __hip_bfloat16 h[4]; s16x4 q; } u;
        u.h[0] = __float2bfloat16(f.x);
        u.h[1] = __float2bfloat16(f.y);
        u.h[2] = __float2bfloat16(f.z);
        u.h[3] = __float2bfloat16(f.w);
        *(s16x4*)(wo_bf + i) = u.q;
    } else if (lin < 5056) {
        const int widx = lin - 4864;         // 0..191
        const int w    = widx >> 6;          // 0..2
        const int tile = widx & 63;
        const float* S = (w == 0) ? Wq : (w == 1) ? Wk : Wv;
        __hip_bfloat16* Dt = (w == 0) ? WqT : (w == 1) ? WkT : WvT;
        const int o0  = (tile & 7) * 64;
        const int c0t = (tile >> 3) * 64;

        const int n_l = tid & 63;            // src col (c)
        const int c_b = tid >> 6;
#pragma unroll
        for (int s = 0; s < 16; ++s) {
            int o_l = c_b + s * 4;
            t[o_l * 65 + n_l] = S[(size_t)(o0 + o_l) * 512 + c0t + n_l];
        }
        __syncthreads();

        const int cc = (tid & 7) * 8;        // o-chunk
        const int nb = tid >> 3;             // c-row (0..31)
#pragma unroll
        for (int it = 0; it < 2; ++it) {
            int c_r = nb + it * 32;
            union { __hip_bfloat16 h[8]; int4 v; } u;
#pragma unroll
            for (int w8 = 0; w8 < 8; ++w8)
                u.h[w8] = __float2bfloat16(t[(cc + w8) * 65 + c_r]);
            *(int4*)(&Dt[(size_t)(c0t + c_r) * 512 + o0 + cc]) = u.v;
        }
    } else if (lin == 5056) {
        // wv[c] = sum_o Wk[o,c]*bq[o]
        float a0 = 0.f, a1 = 0.f;
        for (int o = 0; o < 512; ++o) {
            float bb = bq[o];
            a0 += Wk[(size_t)o * 512 + tid] * bb;
            a1 += Wk[(size_t)o * 512 + tid + 256] * bb;
        }
        wvbuf[tid] = a0;
        wvbuf[tid + 256] = a1;
    } else {
        // bov[o] = Wo[o,:]·bv
#pragma unroll
        for (int half = 0; half < 2; ++half) {
            int o = tid + half * 256;
            float acc = 0.f;
            for (int c4 = 0; c4 < 128; ++c4) {
                float4 f = *(const float4*)(Wo + (size_t)o * 512 + c4 * 4);
                float4 g = *(const float4*)(bv + c4 * 4);
                acc += f.x * g.x + f.y * g.y + f.z * g.z + f.w * g.w;
            }
            bovbuf[o] = acc;
        }
    }
}

// ---------------------------------------------------------------------------
extern "C" void kernel_launch(void* const* d_in, const int* in_sizes, int n_in,
                              void* d_out, int out_size, void* d_ws, size_t ws_size,
                              hipStream_t stream)
{
    const float* locx = (const float*)d_in[0];
    const float* glox = (const float*)d_in[1];
    const float* Wq = (const float*)d_in[2];
    const float* bq = (const float*)d_in[3];
    const float* Wk = (const float*)d_in[4];
    const float* bk = (const float*)d_in[5];   // unused: u[n],c0 cancel in softmax
    const float* Wv = (const float*)d_in[6];
    const float* bv = (const float*)d_in[7];
    const float* Wo = (const float*)d_in[8];
    const float* bo = (const float*)d_in[9];
    float* out = (float*)d_out;
    (void)bk;

    const int C = C_DIM, N = N_PIX;
    const size_t WB   = (size_t)C * C * 2;             // 0.5 MB bf16 mat
    const size_t szX  = (size_t)N_BATCH * N * C * 2;   // 18.87 MB
    const size_t szP1 = (size_t)N * N * 2;
    const size_t szRP = (size_t)NJB * N_BATCH * N * 4;
    const size_t szV  = (size_t)N_BATCH * N * 4;       // vvec

    char* ws = (char*)d_ws;
    size_t off = 0;
    auto alloc = [&](size_t bytes) {
        char* p = ws + off;
        off += (bytes + 255) & ~(size_t)255;
        return p;
    };
    __hip_bfloat16* wo_bf = (__hip_bfloat16*)alloc(WB);
    __hip_bfloat16* WqT   = (__hip_bfloat16*)alloc(WB);
    __hip_bfloat16* WkT   = (__hip_bfloat16*)alloc(WB);
    __hip_bfloat16* WvT   = (__hip_bfloat16*)alloc(WB);
    __hip_bfloat16* matT  = (__hip_bfloat16*)alloc(WB);
    __hip_bfloat16* Wov   = (__hip_bfloat16*)alloc(WB);
    float*          wvb   = (float*)alloc(512 * 4);
    float*          bovb  = (float*)alloc(512 * 4);
    float*          vvec  = (float*)alloc(szV);
    __hip_bfloat16* Xlt   = (__hip_bfloat16*)alloc(szX);
    __hip_bfloat16* Xgt   = (__hip_bfloat16*)alloc(szX);
    __hip_bfloat16* Tm    = (__hip_bfloat16*)alloc(szX);
    __hip_bfloat16* Vp    = (__hip_bfloat16*)alloc(szX);
    float*          rp    = (float*)alloc(szRP);
    const size_t fixed = off;
    bool full = (ws_size >= fixed + 8 * szP1 + 4096);
    __hip_bfloat16* Pu = (__hip_bfloat16*)alloc(full ? 8 * szP1 : szP1);

    const dim3 blk(256);

    prep<<<dim3(5058), blk, 0, stream>>>(locx, glox, Xlt, Xgt,
                                         Wq, Wk, Wv, Wo, wo_bf, WqT, WkT, WvT,
                                         bq, bv, wvb, bovb);
    wmix<<<dim3(104), blk, 0, stream>>>(WkT, WqT, wo_bf, WvT, matT, Wov,
                                        Xgt, wvb, vvec);
    proj2<<<dim3(16 * 72), blk, 0, stream>>>(Xlt, Xgt, matT, Wov, bovb, Tm, Vp);

    if (full) {
        s_only<8><<<dim3(8 * 81), dim3(512), 0, stream>>>(
            Tm, Xgt, Pu, rp, vvec, 0, (long)N * N);
        pv_out<8><<<dim3(8 * 144), blk, 0, stream>>>(
            Vp, Pu, out, bo, rp, 0, (long)N * N);
    } else {
        for (int r = 0; r < N_BATCH; ++r) {
            s_only<1><<<dim3(81), dim3(512), 0, stream>>>(
                Tm, Xgt, Pu, rp, vvec, r, 0);
            pv_out<1><<<dim3(144), blk, 0, stream>>>(
                Vp, Pu, out, bo, rp, r, 0);
        }
    }
}